// Round 12
// baseline (4810.135 us; speedup 1.0000x reference)
//
#include <hip/hip_runtime.h>
#include <cstddef>

#define NS 26

typedef short bf16x8 __attribute__((ext_vector_type(8)));
typedef float f32x4 __attribute__((ext_vector_type(4)));

__device__ __forceinline__ float tanh_fast(float x) { return 1.f - 2.f / (__expf(2.f * x) + 1.f); }
__device__ __forceinline__ float sigf(float x) { return 1.f / (1.f + __expf(-x)); }
__device__ __forceinline__ unsigned short f2bf(float x) {
    unsigned int u = __float_as_uint(x);
    return (unsigned short)((u + 0x7FFFu + ((u >> 16) & 1u)) >> 16);
}

// Coherent (cross-XCD, L2-bypassing) access helpers for intra-kernel handoffs.
#define CSTORED(p, v) asm volatile("global_store_dword %0, %1, off sc0 sc1" :: "v"(p), "v"(v) : "memory")
#define CWAIT() asm volatile("s_waitcnt vmcnt(0)" ::: "memory")
#define CLOADF4(dst, p) asm volatile("global_load_dwordx4 %0, %1, off sc0 sc1\n\ts_waitcnt vmcnt(0)" : "=v"(dst) : "v"(p) : "memory")

__device__ __forceinline__ void spinwait(int* f, int target) {
    while (__hip_atomic_load(f, __ATOMIC_ACQUIRE, __HIP_MEMORY_SCOPE_AGENT) < target)
        __builtin_amdgcn_s_sleep(2);
}
__device__ __forceinline__ void flag_add(int* f) {
    __hip_atomic_fetch_add(f, 1, __ATOMIC_RELEASE, __HIP_MEMORY_SCOPE_AGENT);
}

// ---------------- merged setup (range-dispatched) ----------------
// [0,256): W_i2h->Wi2hb | [256,512): W_h2h->Wh2hb | [512,560): W_gen->Wgenb
// [560,1072): W_ih->Wgi perm | [1072,1584): W_hh->Wgh perm | [1584,2352): Wtok_p
// [2352,2360): bsum_p | [2360,18744): batch_H->bH
// [18744,18872): zero hbuf1 | [18872,19128): zero cst | [19128]: zero flags
__global__ __launch_bounds__(256) void setup_all(
    const float* __restrict__ W_i2h, const float* __restrict__ W_h2h,
    const float* __restrict__ W_gen, const float* __restrict__ W_ih,
    const float* __restrict__ W_hh,  const float* __restrict__ b_ih,
    const float* __restrict__ b_hh,  const float* __restrict__ batch_H,
    unsigned short* __restrict__ Wi2hb, unsigned short* __restrict__ Wh2hb,
    unsigned short* __restrict__ Wgenb, unsigned short* __restrict__ Wgi,
    unsigned short* __restrict__ Wgh,   float* __restrict__ Wtok_p,
    float* __restrict__ bsum_p,         unsigned short* __restrict__ bH,
    unsigned short* __restrict__ hbuf1, float* __restrict__ cst,
    int* __restrict__ flags)
{
    const int b = blockIdx.x, tid = threadIdx.x;
    if (b < 512) {
        const float* src = (b < 256) ? W_i2h : W_h2h;
        unsigned short* dst = (b < 256) ? Wi2hb : Wh2hb;
        const int i = ((b & 255) << 8) + tid;
        float4 v = ((const float4*)src)[i];
        ushort4 o; o.x = f2bf(v.x); o.y = f2bf(v.y); o.z = f2bf(v.z); o.w = f2bf(v.w);
        ((ushort4*)dst)[i] = o;
    } else if (b < 560) {
        const int i = ((b - 512) << 8) + tid;
        float4 v = ((const float4*)W_gen)[i];
        ushort4 o; o.x = f2bf(v.x); o.y = f2bf(v.y); o.z = f2bf(v.z); o.w = f2bf(v.w);
        ((ushort4*)Wgenb)[i] = o;
    } else if (b < 1584) {
        const int isI = (b < 1072);
        const int i = ((b - (isI ? 560 : 1072)) << 8) + tid;
        const int np = i >> 6, k8 = (i & 63) << 3;
        const int h = np >> 2, g = np & 3;
        const float* p = (isI ? W_ih : W_hh) + (size_t)(g * 512 + h) * (isI ? 608 : 512) + k8;
        unsigned short* dst = isI ? Wgi : Wgh;
        float4 v0 = *(const float4*)p, v1 = *(const float4*)(p + 4);
        ushort4 o0, o1;
        o0.x = f2bf(v0.x); o0.y = f2bf(v0.y); o0.z = f2bf(v0.z); o0.w = f2bf(v0.w);
        o1.x = f2bf(v1.x); o1.y = f2bf(v1.y); o1.z = f2bf(v1.z); o1.w = f2bf(v1.w);
        *(ushort4*)(dst + (size_t)np * 512 + k8) = o0;
        *(ushort4*)(dst + (size_t)np * 512 + k8 + 4) = o1;
    } else if (b < 2352) {
        const int i = ((b - 1584) << 8) + tid;
        const int t = i >> 11, np = i & 2047;
        const int h = np >> 2, g = np & 3;
        Wtok_p[i] = W_ih[(size_t)(g * 512 + h) * 608 + 512 + t];
    } else if (b < 2360) {
        const int i = ((b - 2352) << 8) + tid;
        const int h = i >> 2, g = i & 3, n = g * 512 + h;
        bsum_p[i] = b_ih[n] + b_hh[n];
    } else if (b < 18744) {
        const int i = ((b - 2360) << 8) + tid;
        float4 v = ((const float4*)batch_H)[i];
        ushort4 o; o.x = f2bf(v.x); o.y = f2bf(v.y); o.z = f2bf(v.z); o.w = f2bf(v.w);
        ((ushort4*)bH)[i] = o;
    } else if (b < 18872) {
        ((uint4*)hbuf1)[((b - 18744) << 8) + tid] = uint4{0, 0, 0, 0};
    } else if (b < 19128) {
        ((uint4*)cst)[((b - 18872) << 8) + tid] = uint4{0, 0, 0, 0};
    } else {
        for (int i = tid; i < NS * 24; i += 256) flags[i] = 0;
    }
}

// ---------------------------------------------------------------------------
// bf16 NT MFMA GEMM (proven). MODE 0: bf16 out. MODE 3: f32+bias masked.
// SWZ 1: H_proj XCD remap (grid dim3(512,8)).
// ---------------------------------------------------------------------------
template <int MODE, int SWZ>
__global__ __launch_bounds__(256) void gemm_bf16(
    const unsigned short* __restrict__ A, int lda,
    const unsigned short* __restrict__ B, int ldb,
    void* __restrict__ Cout, int ldc,
    const float* __restrict__ bias, int K, int Nreal)
{
    __shared__ unsigned short As[2][64][72];
    __shared__ unsigned short Bs[2][64][72];
    const int tid = threadIdx.x;
    int bm, bn;
    if (SWZ == 1) {
        const int l = blockIdx.x + (blockIdx.y << 9);
        const int cc = l & 7, k = l >> 3;
        bm = ((cc << 6) + (k >> 3)) << 6;
        bn = (k & 7) << 6;
    } else {
        bm = blockIdx.y << 6;
        bn = blockIdx.x << 6;
    }
    const int w = tid >> 6, lane = tid & 63;
    const int wr = w >> 1, wc = w & 1;
    const int srow = tid >> 2, schunk = (tid & 3) << 4;
    int brow = bn + srow;
    if (MODE == 3) brow = min(brow, Nreal - 1);
    const unsigned short* Ap = A + (size_t)(bm + srow) * lda + schunk;
    const unsigned short* Bp = B + (size_t)brow * ldb + schunk;
    const int fr = lane & 15, fq = lane >> 4;

    uint4 ra0, ra1, rb0, rb1;
    f32x4 acc[2][2];
#pragma unroll
    for (int i = 0; i < 2; i++)
#pragma unroll
        for (int j = 0; j < 2; j++) acc[i][j] = f32x4{0.f, 0.f, 0.f, 0.f};

    const int NTk = K >> 6;
#define LOADR(t) { ra0 = *(const uint4*)(Ap + ((t) << 6)); ra1 = *(const uint4*)(Ap + ((t) << 6) + 8); \
                   rb0 = *(const uint4*)(Bp + ((t) << 6)); rb1 = *(const uint4*)(Bp + ((t) << 6) + 8); }
#define WRITEB(cb) { *(uint4*)&As[cb][srow][schunk] = ra0; *(uint4*)&As[cb][srow][schunk + 8] = ra1; \
                     *(uint4*)&Bs[cb][srow][schunk] = rb0; *(uint4*)&Bs[cb][srow][schunk + 8] = rb1; }
    LOADR(0); WRITEB(0);
    LOADR(1);
    __syncthreads();
    for (int t = 0; t < NTk; t++) {
        const int cb = t & 1;
        if (t + 1 < NTk) WRITEB(cb ^ 1);
        if (t + 2 < NTk) LOADR(t + 2);
        bf16x8 af[2][2], bfr[2][2];
#pragma unroll
        for (int fi = 0; fi < 2; fi++)
#pragma unroll
            for (int ks = 0; ks < 2; ks++) {
                af[fi][ks]  = *(const bf16x8*)&As[cb][(wr << 5) + (fi << 4) + fr][(ks << 5) + (fq << 3)];
                bfr[fi][ks] = *(const bf16x8*)&Bs[cb][(wc << 5) + (fi << 4) + fr][(ks << 5) + (fq << 3)];
            }
#pragma unroll
        for (int fi = 0; fi < 2; fi++)
#pragma unroll
            for (int fj = 0; fj < 2; fj++)
#pragma unroll
                for (int ks = 0; ks < 2; ks++)
                    acc[fi][fj] = __builtin_amdgcn_mfma_f32_16x16x32_bf16(
                        af[fi][ks], bfr[fj][ks], acc[fi][fj], 0, 0, 0);
        __syncthreads();
    }
#undef LOADR
#undef WRITEB
#pragma unroll
    for (int fi = 0; fi < 2; fi++) {
        const int mbase = bm + (wr << 5) + (fi << 4) + (fq << 2);
#pragma unroll
        for (int fj = 0; fj < 2; fj++) {
            const int n = bn + (wc << 5) + (fj << 4) + fr;
            f32x4 v = acc[fi][fj];
            if (MODE == 0) {
                unsigned short* C = (unsigned short*)Cout;
#pragma unroll
                for (int r = 0; r < 4; r++) C[(size_t)(mbase + r) * ldc + n] = f2bf(v[r]);
            } else {
                if (n < Nreal) {
                    float* C = (float*)Cout;
                    const float bb = bias[n];
#pragma unroll
                    for (int r = 0; r < 4; r++) C[(size_t)(mbase + r) * ldc + n] = v[r] + bb;
                }
            }
        }
    }
}

// ---------------------------------------------------------------------------
// Fused per-step kernel: 1024 blocks x 256 thr, layered producer->consumer DAG.
//  bid [0,256):    ph role  (R7 gemm_ph body; coherent stores + flag)
//  bid [256,768):  attn role (R7 attn body, b=bid-256; waits ph flag)
//  bid [768,1024): gates role (R10 gates body; waits ctx flag)
// Hang-free: producers never spin; roles ordered by ascending blockIdx;
// all 1024 blocks co-resident (256thr, <=36.9KB LDS, <=128 VGPR).
// ---------------------------------------------------------------------------
__global__ __launch_bounds__(256, 4) void step_fused(
    const unsigned short* __restrict__ Hproj,
    const unsigned short* __restrict__ bH,
    const unsigned short* __restrict__ hprev,
    unsigned short* __restrict__ hcur,
    const unsigned short* __restrict__ Wh2hb,
    const float* __restrict__ b_h2h,
    const float* __restrict__ w_score,
    unsigned short* __restrict__ ctx,
    float* __restrict__ ph,
    const unsigned short* __restrict__ Wgi,
    const unsigned short* __restrict__ Wgh,
    const float* __restrict__ bsum_p,
    const float* __restrict__ Wtok_p,
    const int* __restrict__ text,
    float* __restrict__ cst,
    unsigned short* __restrict__ hs,
    int sstep, int* __restrict__ flags)
{
    __shared__ __align__(16) char smem[36864];
    int* fph = flags + sstep * 24;   // [16] ph m-tile counters (each -> 16)
    int* fat = fph + 16;             // [8] ctx 64-row-tile counters (each -> 64)
    const int bid = blockIdx.x, tid = threadIdx.x;
    const int w = tid >> 6, lane = tid & 63;
    const int fr = lane & 15, fq = lane >> 4;

    if (bid < 256) {
        // ================= ph role: ph = hprev @ Wh2h^T + b_h2h =================
        unsigned short (*As)[32][72] = (unsigned short(*)[32][72])smem;
        unsigned short (*Bs)[32][72] = (unsigned short(*)[32][72])(smem + 9216);
        const int m0 = (bid >> 4) << 5;
        const int n0 = (bid & 15) << 5;
        const int mf = w >> 1, nf = w & 1;
        const int srow = tid >> 3, schunk = (tid & 7) << 3;
        const unsigned short* Ap = hprev + (size_t)(m0 + srow) * 512 + schunk;
        const unsigned short* Bp = Wh2hb + (size_t)(n0 + srow) * 512 + schunk;

        uint4 ra, rb;
        f32x4 acc = {0.f, 0.f, 0.f, 0.f};
        ra = *(const uint4*)Ap; rb = *(const uint4*)Bp;
        *(uint4*)&As[0][srow][schunk] = ra;
        *(uint4*)&Bs[0][srow][schunk] = rb;
        ra = *(const uint4*)(Ap + 64); rb = *(const uint4*)(Bp + 64);
        __syncthreads();
        for (int t = 0; t < 8; t++) {
            const int cb = t & 1;
            if (t + 1 < 8) { *(uint4*)&As[cb ^ 1][srow][schunk] = ra;
                             *(uint4*)&Bs[cb ^ 1][srow][schunk] = rb; }
            if (t + 2 < 8) { ra = *(const uint4*)(Ap + ((t + 2) << 6));
                             rb = *(const uint4*)(Bp + ((t + 2) << 6)); }
            const bf16x8 a0 = *(const bf16x8*)&As[cb][(mf << 4) + fr][(fq << 3)];
            const bf16x8 a1 = *(const bf16x8*)&As[cb][(mf << 4) + fr][32 + (fq << 3)];
            const bf16x8 b0 = *(const bf16x8*)&Bs[cb][(nf << 4) + fr][(fq << 3)];
            const bf16x8 b1 = *(const bf16x8*)&Bs[cb][(nf << 4) + fr][32 + (fq << 3)];
            acc = __builtin_amdgcn_mfma_f32_16x16x32_bf16(a0, b0, acc, 0, 0, 0);
            acc = __builtin_amdgcn_mfma_f32_16x16x32_bf16(a1, b1, acc, 0, 0, 0);
            __syncthreads();
        }
        const int n = n0 + (nf << 4) + fr;
        const float bb = b_h2h[n];
#pragma unroll
        for (int r = 0; r < 4; r++) {
            const float v = acc[r] + bb;
            float* p = ph + (size_t)(m0 + (mf << 4) + (fq << 2) + r) * 512 + n;
            CSTORED(p, v);
        }
        CWAIT();
        __syncthreads();
        if (tid == 0) flag_add(&fph[bid >> 4]);
    } else if (bid < 768) {
        // ================= attn role: 1 batch b = bid-256 =================
        float* s_e  = (float*)smem;
        float* s_al = (float*)(smem + 256);
        const int b = bid - 256;
        if (tid == 0) spinwait(&fph[b >> 5], 16);
        __syncthreads();
        const int h0 = lane * 8;
        f32x4 pv0, pv1;
        CLOADF4(pv0, ph + (size_t)b * 512 + h0);
        CLOADF4(pv1, ph + (size_t)b * 512 + h0 + 4);
        const float4 w0 = *(const float4*)(w_score + h0);
        const float4 w1 = *(const float4*)(w_score + h0 + 4);
        const float rp[8] = {pv0[0], pv0[1], pv0[2], pv0[3], pv1[0], pv1[1], pv1[2], pv1[3]};
        const float rw[8] = {w0.x, w0.y, w0.z, w0.w, w1.x, w1.y, w1.z, w1.w};

        for (int t = w; t < 64; t += 4) {
            const uint4 hv = *(const uint4*)(Hproj + ((size_t)b * 64 + t) * 512 + h0);
            unsigned int ua[4] = {hv.x, hv.y, hv.z, hv.w};
            float acc = 0.f;
#pragma unroll
            for (int j = 0; j < 4; j++) {
                const float e0 = __uint_as_float(ua[j] << 16);
                const float e1 = __uint_as_float(ua[j] & 0xffff0000u);
                acc += tanh_fast(e0 + rp[2 * j]) * rw[2 * j];
                acc += tanh_fast(e1 + rp[2 * j + 1]) * rw[2 * j + 1];
            }
#pragma unroll
            for (int off = 32; off; off >>= 1) acc += __shfl_xor(acc, off);
            if (lane == 0) s_e[t] = acc;
        }
        __syncthreads();
        if (tid < 64) {
            float m = -1e30f;
            for (int t = 0; t < 64; ++t) m = fmaxf(m, s_e[t]);
            float sum = 0.f;
            for (int t = 0; t < 64; ++t) sum += __expf(s_e[t] - m);
            s_al[tid] = __expf(s_e[tid] - m) / sum;
        }
        __syncthreads();
        {
            const unsigned int* bHp = (const unsigned int*)(bH + (size_t)b * 64 * 512);
            float a0 = 0.f, a1 = 0.f;
            for (int t = 0; t < 64; ++t) {
                const unsigned int u = bHp[t * 256 + tid];
                const float al = s_al[t];
                a0 = fmaf(al, __uint_as_float(u << 16), a0);
                a1 = fmaf(al, __uint_as_float(u & 0xffff0000u), a1);
            }
            const unsigned int o = ((unsigned int)f2bf(a1) << 16) | (unsigned int)f2bf(a0);
            unsigned int* cp = (unsigned int*)(ctx + (size_t)b * 512) + tid;
            CSTORED(cp, o);
        }
        CWAIT();
        __syncthreads();
        if (tid == 0) flag_add(&fat[b >> 6]);
    } else {
        // ================= gates role: l = bid-768 =================
        unsigned short (*As)[64][72] = (unsigned short(*)[64][72])smem;
        unsigned short (*Bs)[64][72] = (unsigned short(*)[64][72])(smem + 18432);
        float (*gls)[68] = (float(*)[68])smem;

        const int l = bid - 768;
        const int cc = l & 7, kq = l >> 3;
        const int nblk = (cc << 2) + (kq >> 3);
        const int m0 = (kq & 7) << 6;
        const int bn_ = nblk << 6;
        const int wr = w >> 1, wc = w & 1;
        const int srow = tid >> 2, schunk = (tid & 3) << 4;

        if (tid == 0) spinwait(&fat[(l >> 3) & 7], 64);
        __syncthreads();

        const unsigned short* Ac = ctx   + (size_t)(m0 + srow) * 512 + schunk;
        const unsigned short* Ah = hprev + (size_t)(m0 + srow) * 512 + schunk;
        const unsigned short* Bi = Wgi + (size_t)(bn_ + srow) * 512 + schunk;
        const unsigned short* Bh = Wgh + (size_t)(bn_ + srow) * 512 + schunk;

        uint4 ra0, ra1, rb0, rb1;
        f32x4 acc[2][2];
#pragma unroll
        for (int i = 0; i < 2; i++)
#pragma unroll
            for (int j = 0; j < 2; j++) acc[i][j] = f32x4{0.f, 0.f, 0.f, 0.f};

#define GLOAD(t) { const int tt = (t); \
    if (tt < 8) { \
        const unsigned short* ap = Ac + (tt << 6); \
        asm volatile("global_load_dwordx4 %0, %2, off sc0 sc1\n\t" \
                     "global_load_dwordx4 %1, %3, off sc0 sc1\n\t" \
                     "s_waitcnt vmcnt(0)" \
                     : "=&v"(ra0), "=&v"(ra1) : "v"(ap), "v"(ap + 8) : "memory"); \
        const unsigned short* bp = Bi + (tt << 6); \
        rb0 = *(const uint4*)bp; rb1 = *(const uint4*)(bp + 8); \
    } else { \
        const unsigned short* ap = Ah + ((tt - 8) << 6); \
        const unsigned short* bp = Bh + ((tt - 8) << 6); \
        ra0 = *(const uint4*)ap; ra1 = *(const uint4*)(ap + 8); \
        rb0 = *(const uint4*)bp; rb1 = *(const uint4*)(bp + 8); } }
#define WRITEB(cb) { *(uint4*)&As[cb][srow][schunk] = ra0; *(uint4*)&As[cb][srow][schunk + 8] = ra1; \
                     *(uint4*)&Bs[cb][srow][schunk] = rb0; *(uint4*)&Bs[cb][srow][schunk + 8] = rb1; }
        GLOAD(0); WRITEB(0);
        GLOAD(1);
        __syncthreads();
        for (int t = 0; t < 16; t++) {
            const int cb = t & 1;
            if (t + 1 < 16) WRITEB(cb ^ 1);
            if (t + 2 < 16) GLOAD(t + 2);
            bf16x8 af[2][2], bfr[2][2];
#pragma unroll
            for (int fi = 0; fi < 2; fi++)
#pragma unroll
                for (int ks = 0; ks < 2; ks++) {
                    af[fi][ks]  = *(const bf16x8*)&As[cb][(wr << 5) + (fi << 4) + fr][(ks << 5) + (fq << 3)];
                    bfr[fi][ks] = *(const bf16x8*)&Bs[cb][(wc << 5) + (fi << 4) + fr][(ks << 5) + (fq << 3)];
                }
#pragma unroll
            for (int fi = 0; fi < 2; fi++)
#pragma unroll
                for (int fj = 0; fj < 2; fj++)
#pragma unroll
                    for (int ks = 0; ks < 2; ks++)
                        acc[fi][fj] = __builtin_amdgcn_mfma_f32_16x16x32_bf16(
                            af[fi][ks], bfr[fj][ks], acc[fi][fj], 0, 0, 0);
            __syncthreads();
        }
#undef GLOAD
#undef WRITEB
#pragma unroll
        for (int fi = 0; fi < 2; fi++)
#pragma unroll
            for (int fj = 0; fj < 2; fj++)
#pragma unroll
                for (int r = 0; r < 4; r++)
                    gls[(wr << 5) + (fi << 4) + (fq << 2) + r][(wc << 5) + (fj << 4) + fr] = acc[fi][fj][r];
        __syncthreads();

        const int hbase = nblk << 4;
#pragma unroll
        for (int p = 0; p < 4; p++) {
            const int idx = (p << 8) + tid;
            const int ml = idx >> 4, hl = idx & 15;
            const int mg = m0 + ml, hg = hbase + hl;
            const int tok = text[mg * NS + sstep];
            const float4 gq = *(const float4*)&gls[ml][hl << 2];
            const float4 bq = *(const float4*)&bsum_p[bn_ + (hl << 2)];
            const float4 wq = *(const float4*)&Wtok_p[(size_t)tok * 2048 + bn_ + (hl << 2)];
            const float i_ = sigf(gq.x + bq.x + wq.x);
            const float f_ = sigf(gq.y + bq.y + wq.y);
            const float g_ = tanh_fast(gq.z + bq.z + wq.z);
            const float o_ = sigf(gq.w + bq.w + wq.w);
            const size_t ci = (size_t)mg * 512 + hg;
            const float cn = fmaf(f_, cst[ci], i_ * g_);
            cst[ci] = cn;
            const unsigned short hv = f2bf(o_ * tanh_fast(cn));
            hs[((size_t)mg * NS + sstep) * 512 + hg] = hv;
            hcur[ci] = hv;
        }
    }
}

// ---------------------------------------------------------------------------
extern "C" void kernel_launch(void* const* d_in, const int* in_sizes, int n_in,
                              void* d_out, int out_size, void* d_ws, size_t ws_size,
                              hipStream_t stream) {
    const float* batch_H = (const float*)d_in[0];
    const int*   text    = (const int*)d_in[1];
    const float* W_i2h   = (const float*)d_in[2];
    const float* W_h2h   = (const float*)d_in[3];
    const float* b_h2h   = (const float*)d_in[4];
    const float* w_score = (const float*)d_in[5];
    const float* W_ih    = (const float*)d_in[6];
    const float* b_ih    = (const float*)d_in[7];
    const float* W_hh    = (const float*)d_in[8];
    const float* b_hh    = (const float*)d_in[9];
    const float* W_gen   = (const float*)d_in[10];
    const float* b_gen   = (const float*)d_in[11];
    float* out = (float*)d_out;

    char* wsp = (char*)d_ws;
    auto alloc = [&](size_t bytes) { char* p = wsp; wsp += (bytes + 255) & ~(size_t)255; return p; };
    unsigned short* bH    = (unsigned short*)alloc(32768ull * 512 * 2);
    unsigned short* Hproj = (unsigned short*)alloc(32768ull * 512 * 2);
    unsigned short* hs    = (unsigned short*)alloc(512ull * NS * 512 * 2);
    unsigned short* hbuf0 = (unsigned short*)alloc(512ull * 512 * 2);
    unsigned short* hbuf1 = (unsigned short*)alloc(512ull * 512 * 2);
    unsigned short* ctx   = (unsigned short*)alloc(512ull * 512 * 2);
    unsigned short* Wi2hb = (unsigned short*)alloc(512ull * 512 * 2);
    unsigned short* Wh2hb = (unsigned short*)alloc(512ull * 512 * 2);
    unsigned short* Wgi   = (unsigned short*)alloc(2048ull * 512 * 2);
    unsigned short* Wgh   = (unsigned short*)alloc(2048ull * 512 * 2);
    unsigned short* Wgenb = (unsigned short*)alloc(96ull * 512 * 2);
    float* ph     = (float*)alloc(512ull * 512 * 4);
    float* cst    = (float*)alloc(512ull * 512 * 4);
    float* bsum_p = (float*)alloc(2048ull * 4);
    float* Wtok_p = (float*)alloc(96ull * 2048 * 4);
    int*   flags  = (int*)alloc(NS * 24 * 4);
    unsigned short* hb[2] = {hbuf0, hbuf1};

    setup_all<<<19129, 256, 0, stream>>>(W_i2h, W_h2h, W_gen, W_ih, W_hh, b_ih, b_hh,
                                         batch_H, Wi2hb, Wh2hb, Wgenb, Wgi, Wgh,
                                         Wtok_p, bsum_p, bH, hbuf1, cst, flags);

    // H_proj = batch_H @ W_i2h^T -> bf16 [32768,512], XCD-swizzled
    gemm_bf16<0, 1><<<dim3(512, 8), 256, 0, stream>>>(bH, 512, Wi2hb, 512, Hproj, 512, nullptr, 512, 0);

    for (int s = 0; s < NS; ++s) {
        step_fused<<<1024, 256, 0, stream>>>(
            Hproj, bH, hb[(s + 1) & 1], hb[s & 1], Wh2hb, b_h2h, w_score,
            ctx, ph, Wgi, Wgh, bsum_p, Wtok_p, text, cst, hs, s, flags);
    }

    // out = hs @ W_gen^T + b_gen (f32, N=96 masked in 128-wide tiles)
    gemm_bf16<3, 0><<<dim3(2, 208), 256, 0, stream>>>(hs, 512, Wgenb, 512, out, 96, b_gen, 512, 96);
}

// Round 13
// 1262.050 us; speedup vs baseline: 3.8114x; 3.8114x over previous
//
#include <hip/hip_runtime.h>
#include <cstddef>

#define NS 26

typedef short bf16x8 __attribute__((ext_vector_type(8)));
typedef float f32x4 __attribute__((ext_vector_type(4)));

__device__ __forceinline__ float tanh_fast(float x) { return 1.f - 2.f / (__expf(2.f * x) + 1.f); }
__device__ __forceinline__ float sigf(float x) { return 1.f / (1.f + __expf(-x)); }
__device__ __forceinline__ unsigned short f2bf(float x) {
    unsigned int u = __float_as_uint(x);
    return (unsigned short)((u + 0x7FFFu + ((u >> 16) & 1u)) >> 16);
}

// ---------------- merged setup (range-dispatched) ----------------
// [0,256): W_i2h->Wi2hb | [256,512): W_h2h->Wh2hb | [512,560): W_gen->Wgenb
// [560,1072): W_ih->Wgi perm | [1072,1584): W_hh->Wgh perm | [1584,2352): Wtok_p
// [2352,2360): bsum_p | [2360,18744): batch_H->bH
// [18744,18872): zero hbuf1 (128 blk) | [18872,19128): zero cst (256 blk)
__global__ __launch_bounds__(256) void setup_all(
    const float* __restrict__ W_i2h, const float* __restrict__ W_h2h,
    const float* __restrict__ W_gen, const float* __restrict__ W_ih,
    const float* __restrict__ W_hh,  const float* __restrict__ b_ih,
    const float* __restrict__ b_hh,  const float* __restrict__ batch_H,
    unsigned short* __restrict__ Wi2hb, unsigned short* __restrict__ Wh2hb,
    unsigned short* __restrict__ Wgenb, unsigned short* __restrict__ Wgi,
    unsigned short* __restrict__ Wgh,   float* __restrict__ Wtok_p,
    float* __restrict__ bsum_p,         unsigned short* __restrict__ bH,
    unsigned short* __restrict__ hbuf1, float* __restrict__ cst)
{
    const int b = blockIdx.x, tid = threadIdx.x;
    if (b < 512) {
        const float* src = (b < 256) ? W_i2h : W_h2h;
        unsigned short* dst = (b < 256) ? Wi2hb : Wh2hb;
        const int i = ((b & 255) << 8) + tid;
        float4 v = ((const float4*)src)[i];
        ushort4 o; o.x = f2bf(v.x); o.y = f2bf(v.y); o.z = f2bf(v.z); o.w = f2bf(v.w);
        ((ushort4*)dst)[i] = o;
    } else if (b < 560) {
        const int i = ((b - 512) << 8) + tid;
        float4 v = ((const float4*)W_gen)[i];
        ushort4 o; o.x = f2bf(v.x); o.y = f2bf(v.y); o.z = f2bf(v.z); o.w = f2bf(v.w);
        ((ushort4*)Wgenb)[i] = o;
    } else if (b < 1584) {
        const int isI = (b < 1072);
        const int i = ((b - (isI ? 560 : 1072)) << 8) + tid;
        const int np = i >> 6, k8 = (i & 63) << 3;
        const int h = np >> 2, g = np & 3;
        const float* p = (isI ? W_ih : W_hh) + (size_t)(g * 512 + h) * (isI ? 608 : 512) + k8;
        unsigned short* dst = isI ? Wgi : Wgh;
        float4 v0 = *(const float4*)p, v1 = *(const float4*)(p + 4);
        ushort4 o0, o1;
        o0.x = f2bf(v0.x); o0.y = f2bf(v0.y); o0.z = f2bf(v0.z); o0.w = f2bf(v0.w);
        o1.x = f2bf(v1.x); o1.y = f2bf(v1.y); o1.z = f2bf(v1.z); o1.w = f2bf(v1.w);
        *(ushort4*)(dst + (size_t)np * 512 + k8) = o0;
        *(ushort4*)(dst + (size_t)np * 512 + k8 + 4) = o1;
    } else if (b < 2352) {
        const int i = ((b - 1584) << 8) + tid;
        const int t = i >> 11, np = i & 2047;
        const int h = np >> 2, g = np & 3;
        Wtok_p[i] = W_ih[(size_t)(g * 512 + h) * 608 + 512 + t];
    } else if (b < 2360) {
        const int i = ((b - 2352) << 8) + tid;
        const int h = i >> 2, g = i & 3, n = g * 512 + h;
        bsum_p[i] = b_ih[n] + b_hh[n];
    } else if (b < 18744) {
        const int i = ((b - 2360) << 8) + tid;
        float4 v = ((const float4*)batch_H)[i];
        ushort4 o; o.x = f2bf(v.x); o.y = f2bf(v.y); o.z = f2bf(v.z); o.w = f2bf(v.w);
        ((ushort4*)bH)[i] = o;
    } else if (b < 18872) {
        ((uint4*)hbuf1)[((b - 18744) << 8) + tid] = uint4{0, 0, 0, 0};
    } else {
        ((uint4*)cst)[((b - 18872) << 8) + tid] = uint4{0, 0, 0, 0};
    }
}

// ---------------------------------------------------------------------------
// bf16 NT MFMA GEMM (proven). MODE 0: bf16 out. MODE 3: f32+bias masked.
// SWZ 1: H_proj XCD remap (grid dim3(512,8)).
// ---------------------------------------------------------------------------
template <int MODE, int SWZ>
__global__ __launch_bounds__(256) void gemm_bf16(
    const unsigned short* __restrict__ A, int lda,
    const unsigned short* __restrict__ B, int ldb,
    void* __restrict__ Cout, int ldc,
    const float* __restrict__ bias, int K, int Nreal)
{
    __shared__ unsigned short As[2][64][72];
    __shared__ unsigned short Bs[2][64][72];
    const int tid = threadIdx.x;
    int bm, bn;
    if (SWZ == 1) {
        const int l = blockIdx.x + (blockIdx.y << 9);
        const int cc = l & 7, k = l >> 3;
        bm = ((cc << 6) + (k >> 3)) << 6;
        bn = (k & 7) << 6;
    } else {
        bm = blockIdx.y << 6;
        bn = blockIdx.x << 6;
    }
    const int w = tid >> 6, lane = tid & 63;
    const int wr = w >> 1, wc = w & 1;
    const int srow = tid >> 2, schunk = (tid & 3) << 4;
    int brow = bn + srow;
    if (MODE == 3) brow = min(brow, Nreal - 1);
    const unsigned short* Ap = A + (size_t)(bm + srow) * lda + schunk;
    const unsigned short* Bp = B + (size_t)brow * ldb + schunk;
    const int fr = lane & 15, fq = lane >> 4;

    uint4 ra0, ra1, rb0, rb1;
    f32x4 acc[2][2];
#pragma unroll
    for (int i = 0; i < 2; i++)
#pragma unroll
        for (int j = 0; j < 2; j++) acc[i][j] = f32x4{0.f, 0.f, 0.f, 0.f};

    const int NTk = K >> 6;
#define LOADR(t) { ra0 = *(const uint4*)(Ap + ((t) << 6)); ra1 = *(const uint4*)(Ap + ((t) << 6) + 8); \
                   rb0 = *(const uint4*)(Bp + ((t) << 6)); rb1 = *(const uint4*)(Bp + ((t) << 6) + 8); }
#define WRITEB(cb) { *(uint4*)&As[cb][srow][schunk] = ra0; *(uint4*)&As[cb][srow][schunk + 8] = ra1; \
                     *(uint4*)&Bs[cb][srow][schunk] = rb0; *(uint4*)&Bs[cb][srow][schunk + 8] = rb1; }
    LOADR(0); WRITEB(0);
    LOADR(1);
    __syncthreads();
    for (int t = 0; t < NTk; t++) {
        const int cb = t & 1;
        if (t + 1 < NTk) WRITEB(cb ^ 1);
        if (t + 2 < NTk) LOADR(t + 2);
        bf16x8 af[2][2], bfr[2][2];
#pragma unroll
        for (int fi = 0; fi < 2; fi++)
#pragma unroll
            for (int ks = 0; ks < 2; ks++) {
                af[fi][ks]  = *(const bf16x8*)&As[cb][(wr << 5) + (fi << 4) + fr][(ks << 5) + (fq << 3)];
                bfr[fi][ks] = *(const bf16x8*)&Bs[cb][(wc << 5) + (fi << 4) + fr][(ks << 5) + (fq << 3)];
            }
#pragma unroll
        for (int fi = 0; fi < 2; fi++)
#pragma unroll
            for (int fj = 0; fj < 2; fj++)
#pragma unroll
                for (int ks = 0; ks < 2; ks++)
                    acc[fi][fj] = __builtin_amdgcn_mfma_f32_16x16x32_bf16(
                        af[fi][ks], bfr[fj][ks], acc[fi][fj], 0, 0, 0);
        __syncthreads();
    }
#undef LOADR
#undef WRITEB
#pragma unroll
    for (int fi = 0; fi < 2; fi++) {
        const int mbase = bm + (wr << 5) + (fi << 4) + (fq << 2);
#pragma unroll
        for (int fj = 0; fj < 2; fj++) {
            const int n = bn + (wc << 5) + (fj << 4) + fr;
            f32x4 v = acc[fi][fj];
            if (MODE == 0) {
                unsigned short* C = (unsigned short*)Cout;
#pragma unroll
                for (int r = 0; r < 4; r++) C[(size_t)(mbase + r) * ldc + n] = f2bf(v[r]);
            } else {
                if (n < Nreal) {
                    float* C = (float*)Cout;
                    const float bb = bias[n];
#pragma unroll
                    for (int r = 0; r < 4; r++) C[(size_t)(mbase + r) * ldc + n] = v[r] + bb;
                }
            }
        }
    }
}

// ---------------------------------------------------------------------------
// Fused ph-recompute + attention. 256 blocks x 512 thr, 2 batches/block.
// Phase 0: each wave w computes ph[0..1][64w..64w+64) = h[2x512] @ Wh2h^T
//          via MFMA with A rows 0-1 = the 2 batches (rows 2-15 duplicates,
//          their D rows never read). B frags read DIRECT global->VGPR
//          (Wh2h L2-resident per XCD; no LDS staging, no extra barriers).
// Phase 1: scores -> softmax -> context (proven R10 structure).
// ---------------------------------------------------------------------------
__global__ __launch_bounds__(512) void attn2_kernel(
    const unsigned short* __restrict__ Hproj,   // [B*64][512] bf16
    const unsigned short* __restrict__ hprev,   // [B][512] bf16
    const unsigned short* __restrict__ Wh2hb,   // [512][512] bf16
    const float* __restrict__ b_h2h,            // [512]
    const float* __restrict__ w_score,          // [512]
    const unsigned short* __restrict__ bH,      // [B*64][512] bf16
    unsigned short* __restrict__ ctx)           // [B][512] bf16
{
    __shared__ unsigned short s_h[2][512];
    __shared__ float s_ph[2][512];
    __shared__ float s_e[2][64];
    __shared__ float s_al[2][64];
    const int bid = blockIdx.x, tid = threadIdx.x;
    const int b0 = bid << 1;
    const int w = tid >> 6, lane = tid & 63;
    const int fr = lane & 15, fq = lane >> 4;

    // stage h (bf16) for both batches: 512 u32 total
    {
        const int q = tid >> 8, p = tid & 255;
        ((unsigned int*)s_h[q])[p] =
            ((const unsigned int*)(hprev + (size_t)(b0 + q) * 512))[p];
    }
    __syncthreads();

    // ---- Phase 0: ph via MFMA, wave w -> cols [64w, 64w+64) ----
    {
        const int n0 = w << 6;
        f32x4 acc[4];
#pragma unroll
        for (int j = 0; j < 4; j++) acc[j] = f32x4{0.f, 0.f, 0.f, 0.f};
#pragma unroll
        for (int ks = 0; ks < 16; ks++) {
            const bf16x8 av = *(const bf16x8*)&s_h[fr & 1][(ks << 5) + (fq << 3)];
#pragma unroll
            for (int fj = 0; fj < 4; fj++) {
                const bf16x8 bv = *(const bf16x8*)(
                    Wh2hb + (size_t)(n0 + (fj << 4) + fr) * 512 + (ks << 5) + (fq << 3));
                acc[fj] = __builtin_amdgcn_mfma_f32_16x16x32_bf16(av, bv, acc[fj], 0, 0, 0);
            }
        }
        // D layout: col = lane&15 (=fr), row = fq*4 + r; rows 0,1 = batches
        if (fq == 0) {
#pragma unroll
            for (int fj = 0; fj < 4; fj++) {
                const int n = n0 + (fj << 4) + fr;
                const float bb = b_h2h[n];
                s_ph[0][n] = acc[fj][0] + bb;
                s_ph[1][n] = acc[fj][1] + bb;
            }
        }
    }
    __syncthreads();

    // ---- Phase 1: scores -> softmax -> ctx. waves 0-3 -> b0, 4-7 -> b0+1 ----
    const int q = w >> 2;
    const int wq = w & 3;
    const int bb = b0 + q;
    const int h0 = lane * 8;

    const float4 p0 = *(const float4*)&s_ph[q][h0];
    const float4 p1 = *(const float4*)&s_ph[q][h0 + 4];
    const float4 w0 = *(const float4*)(w_score + h0);
    const float4 w1 = *(const float4*)(w_score + h0 + 4);
    const float rp[8] = {p0.x, p0.y, p0.z, p0.w, p1.x, p1.y, p1.z, p1.w};
    const float rw[8] = {w0.x, w0.y, w0.z, w0.w, w1.x, w1.y, w1.z, w1.w};

    for (int t = wq; t < 64; t += 4) {
        const uint4 hv = *(const uint4*)(Hproj + ((size_t)bb * 64 + t) * 512 + h0);
        unsigned int ua[4] = {hv.x, hv.y, hv.z, hv.w};
        float acc = 0.f;
#pragma unroll
        for (int j = 0; j < 4; j++) {
            const float e0 = __uint_as_float(ua[j] << 16);
            const float e1 = __uint_as_float(ua[j] & 0xffff0000u);
            acc += tanh_fast(e0 + rp[2 * j]) * rw[2 * j];
            acc += tanh_fast(e1 + rp[2 * j + 1]) * rw[2 * j + 1];
        }
#pragma unroll
        for (int off = 32; off; off >>= 1) acc += __shfl_xor(acc, off);
        if (lane == 0) s_e[q][t] = acc;
    }
    __syncthreads();
    if ((tid & 255) < 64) {
        const int sq = tid >> 8;
        float m = -1e30f;
        for (int t = 0; t < 64; ++t) m = fmaxf(m, s_e[sq][t]);
        float sum = 0.f;
        for (int t = 0; t < 64; ++t) sum += __expf(s_e[sq][t] - m);
        s_al[sq][tid & 63] = __expf(s_e[sq][tid & 63] - m) / sum;
    }
    __syncthreads();
    {
        const int p = tid & 255;
        const unsigned int* bHp = (const unsigned int*)(bH + (size_t)bb * 64 * 512);
        float a0 = 0.f, a1 = 0.f;
        for (int t = 0; t < 64; ++t) {
            const unsigned int u = bHp[t * 256 + p];
            const float al = s_al[q][t];
            a0 = fmaf(al, __uint_as_float(u << 16), a0);
            a1 = fmaf(al, __uint_as_float(u & 0xffff0000u), a1);
        }
        const unsigned int o = ((unsigned int)f2bf(a1) << 16) | (unsigned int)f2bf(a0);
        ((unsigned int*)(ctx + (size_t)bb * 512))[p] = o;
    }
}

// ---------------------------------------------------------------------------
// Fused gates GEMM (gate-permuted N) + LSTM pointwise (proven R4/R7/R10).
// ---------------------------------------------------------------------------
__global__ __launch_bounds__(256) void gates_lstm(
    const unsigned short* __restrict__ ctx,
    const unsigned short* __restrict__ hprev,
    const unsigned short* __restrict__ Wgi,
    const unsigned short* __restrict__ Wgh,
    const float* __restrict__ bsum_p,
    const float* __restrict__ Wtok_p,
    const int* __restrict__ text, int sstep,
    float* __restrict__ c,
    unsigned short* __restrict__ hs,
    unsigned short* __restrict__ hnew)
{
    __shared__ __align__(16) char smem[36864];
    unsigned short (*As)[64][72] = (unsigned short(*)[64][72])smem;
    unsigned short (*Bs)[64][72] = (unsigned short(*)[64][72])(smem + 18432);
    float (*gls)[68] = (float(*)[68])smem;

    const int tid = threadIdx.x;
    const int l = blockIdx.x + (blockIdx.y << 5);
    const int cc = l & 7, kq = l >> 3;
    const int nblk = (cc << 2) + (kq >> 3);
    const int m0 = (kq & 7) << 6;
    const int bn_ = nblk << 6;
    const int w = tid >> 6, lane = tid & 63;
    const int wr = w >> 1, wc = w & 1;
    const int srow = tid >> 2, schunk = (tid & 3) << 4;
    const int fr = lane & 15, fq = lane >> 4;

    const unsigned short* Ac = ctx   + (size_t)(m0 + srow) * 512 + schunk;
    const unsigned short* Ah = hprev + (size_t)(m0 + srow) * 512 + schunk;
    const unsigned short* Bi = Wgi + (size_t)(bn_ + srow) * 512 + schunk;
    const unsigned short* Bh = Wgh + (size_t)(bn_ + srow) * 512 + schunk;

    uint4 ra0, ra1, rb0, rb1;
    f32x4 acc[2][2];
#pragma unroll
    for (int i = 0; i < 2; i++)
#pragma unroll
        for (int j = 0; j < 2; j++) acc[i][j] = f32x4{0.f, 0.f, 0.f, 0.f};

#define GLOAD(t) { const int tt = (t); \
    const unsigned short* ap = (tt < 8) ? Ac + (tt << 6) : Ah + ((tt - 8) << 6); \
    const unsigned short* bp = (tt < 8) ? Bi + (tt << 6) : Bh + ((tt - 8) << 6); \
    ra0 = *(const uint4*)ap; ra1 = *(const uint4*)(ap + 8); \
    rb0 = *(const uint4*)bp; rb1 = *(const uint4*)(bp + 8); }
#define WRITEB(cb) { *(uint4*)&As[cb][srow][schunk] = ra0; *(uint4*)&As[cb][srow][schunk + 8] = ra1; \
                     *(uint4*)&Bs[cb][srow][schunk] = rb0; *(uint4*)&Bs[cb][srow][schunk + 8] = rb1; }
    GLOAD(0); WRITEB(0);
    GLOAD(1);
    __syncthreads();
    for (int t = 0; t < 16; t++) {
        const int cb = t & 1;
        if (t + 1 < 16) WRITEB(cb ^ 1);
        if (t + 2 < 16) GLOAD(t + 2);
        bf16x8 af[2][2], bfr[2][2];
#pragma unroll
        for (int fi = 0; fi < 2; fi++)
#pragma unroll
            for (int ks = 0; ks < 2; ks++) {
                af[fi][ks]  = *(const bf16x8*)&As[cb][(wr << 5) + (fi << 4) + fr][(ks << 5) + (fq << 3)];
                bfr[fi][ks] = *(const bf16x8*)&Bs[cb][(wc << 5) + (fi << 4) + fr][(ks << 5) + (fq << 3)];
            }
#pragma unroll
        for (int fi = 0; fi < 2; fi++)
#pragma unroll
            for (int fj = 0; fj < 2; fj++)
#pragma unroll
                for (int ks = 0; ks < 2; ks++)
                    acc[fi][fj] = __builtin_amdgcn_mfma_f32_16x16x32_bf16(
                        af[fi][ks], bfr[fj][ks], acc[fi][fj], 0, 0, 0);
        __syncthreads();
    }
#undef GLOAD
#undef WRITEB
#pragma unroll
    for (int fi = 0; fi < 2; fi++)
#pragma unroll
        for (int fj = 0; fj < 2; fj++)
#pragma unroll
            for (int r = 0; r < 4; r++)
                gls[(wr << 5) + (fi << 4) + (fq << 2) + r][(wc << 5) + (fj << 4) + fr] = acc[fi][fj][r];
    __syncthreads();

    const int hbase = nblk << 4;
#pragma unroll
    for (int p = 0; p < 4; p++) {
        const int idx = (p << 8) + tid;
        const int ml = idx >> 4, hl = idx & 15;
        const int mg = m0 + ml, hg = hbase + hl;
        const int tok = text[mg * NS + sstep];
        const float4 gq = *(const float4*)&gls[ml][hl << 2];
        const float4 bq = *(const float4*)&bsum_p[bn_ + (hl << 2)];
        const float4 wq = *(const float4*)&Wtok_p[(size_t)tok * 2048 + bn_ + (hl << 2)];
        const float i_ = sigf(gq.x + bq.x + wq.x);
        const float f_ = sigf(gq.y + bq.y + wq.y);
        const float g_ = tanh_fast(gq.z + bq.z + wq.z);
        const float o_ = sigf(gq.w + bq.w + wq.w);
        const size_t ci = (size_t)mg * 512 + hg;
        const float cn = fmaf(f_, c[ci], i_ * g_);
        c[ci] = cn;
        const unsigned short hv = f2bf(o_ * tanh_fast(cn));
        hs[((size_t)mg * NS + sstep) * 512 + hg] = hv;
        hnew[ci] = hv;
    }
}

// ---------------------------------------------------------------------------
extern "C" void kernel_launch(void* const* d_in, const int* in_sizes, int n_in,
                              void* d_out, int out_size, void* d_ws, size_t ws_size,
                              hipStream_t stream) {
    const float* batch_H = (const float*)d_in[0];
    const int*   text    = (const int*)d_in[1];
    const float* W_i2h   = (const float*)d_in[2];
    const float* W_h2h   = (const float*)d_in[3];
    const float* b_h2h   = (const float*)d_in[4];
    const float* w_score = (const float*)d_in[5];
    const float* W_ih    = (const float*)d_in[6];
    const float* b_ih    = (const float*)d_in[7];
    const float* W_hh    = (const float*)d_in[8];
    const float* b_hh    = (const float*)d_in[9];
    const float* W_gen   = (const float*)d_in[10];
    const float* b_gen   = (const float*)d_in[11];
    float* out = (float*)d_out;

    char* wsp = (char*)d_ws;
    auto alloc = [&](size_t bytes) { char* p = wsp; wsp += (bytes + 255) & ~(size_t)255; return p; };
    unsigned short* bH    = (unsigned short*)alloc(32768ull * 512 * 2);
    unsigned short* Hproj = (unsigned short*)alloc(32768ull * 512 * 2);
    unsigned short* hs    = (unsigned short*)alloc(512ull * NS * 512 * 2);
    unsigned short* hbuf0 = (unsigned short*)alloc(512ull * 512 * 2);
    unsigned short* hbuf1 = (unsigned short*)alloc(512ull * 512 * 2);
    unsigned short* ctx   = (unsigned short*)alloc(512ull * 512 * 2);
    unsigned short* Wi2hb = (unsigned short*)alloc(512ull * 512 * 2);
    unsigned short* Wh2hb = (unsigned short*)alloc(512ull * 512 * 2);
    unsigned short* Wgi   = (unsigned short*)alloc(2048ull * 512 * 2);
    unsigned short* Wgh   = (unsigned short*)alloc(2048ull * 512 * 2);
    unsigned short* Wgenb = (unsigned short*)alloc(96ull * 512 * 2);
    float* cst    = (float*)alloc(512ull * 512 * 4);
    float* bsum_p = (float*)alloc(2048ull * 4);
    float* Wtok_p = (float*)alloc(96ull * 2048 * 4);
    unsigned short* hb[2] = {hbuf0, hbuf1};

    setup_all<<<19128, 256, 0, stream>>>(W_i2h, W_h2h, W_gen, W_ih, W_hh, b_ih, b_hh,
                                         batch_H, Wi2hb, Wh2hb, Wgenb, Wgi, Wgh,
                                         Wtok_p, bsum_p, bH, hbuf1, cst);

    // H_proj = batch_H @ W_i2h^T -> bf16 [32768,512], XCD-swizzled
    gemm_bf16<0, 1><<<dim3(512, 8), 256, 0, stream>>>(bH, 512, Wi2hb, 512, Hproj, 512, nullptr, 512, 0);

    for (int s = 0; s < NS; ++s) {
        const unsigned short* hprev = hb[(s + 1) & 1];
        attn2_kernel<<<256, 512, 0, stream>>>(Hproj, hprev, Wh2hb, b_h2h, w_score, bH, ctx);
        gates_lstm<<<dim3(32, 8), 256, 0, stream>>>(
            ctx, hprev, Wgi, Wgh, bsum_p, Wtok_p, text, s, cst, hs, hb[s & 1]);
    }

    // out = hs @ W_gen^T + b_gen (f32, N=96 masked in 128-wide tiles)
    gemm_bf16<3, 0><<<dim3(2, 208), 256, 0, stream>>>(hs, 512, Wgenb, 512, out, 96, b_gen, 512, 96);
}

// Round 14
// 948.383 us; speedup vs baseline: 5.0719x; 1.3307x over previous
//
#include <hip/hip_runtime.h>
#include <cstddef>

#define NS 26

typedef short bf16x8 __attribute__((ext_vector_type(8)));
typedef float f32x4 __attribute__((ext_vector_type(4)));

__device__ __forceinline__ float tanh_fast(float x) { return 1.f - 2.f / (__expf(2.f * x) + 1.f); }
__device__ __forceinline__ float sigf(float x) { return 1.f / (1.f + __expf(-x)); }
__device__ __forceinline__ unsigned short f2bf(float x) {
    unsigned int u = __float_as_uint(x);
    return (unsigned short)((u + 0x7FFFu + ((u >> 16) & 1u)) >> 16);
}

// ---------------- merged setup (range-dispatched) ----------------
// [0,256): W_i2h->Wi2hb | [256,512): W_h2h->Wh2hb | [512,560): W_gen->Wgenb
// [560,1072): W_ih->Wgi perm | [1072,1584): W_hh->Wgh perm | [1584,2352): Wtok_p
// [2352,2360): bsum_p | [2360,18744): batch_H->bH
// [18744,18872): zero hbuf1 (128 blk) | [18872,19128): zero cst (256 blk)
__global__ __launch_bounds__(256) void setup_all(
    const float* __restrict__ W_i2h, const float* __restrict__ W_h2h,
    const float* __restrict__ W_gen, const float* __restrict__ W_ih,
    const float* __restrict__ W_hh,  const float* __restrict__ b_ih,
    const float* __restrict__ b_hh,  const float* __restrict__ batch_H,
    unsigned short* __restrict__ Wi2hb, unsigned short* __restrict__ Wh2hb,
    unsigned short* __restrict__ Wgenb, unsigned short* __restrict__ Wgi,
    unsigned short* __restrict__ Wgh,   float* __restrict__ Wtok_p,
    float* __restrict__ bsum_p,         unsigned short* __restrict__ bH,
    unsigned short* __restrict__ hbuf1, float* __restrict__ cst)
{
    const int b = blockIdx.x, tid = threadIdx.x;
    if (b < 512) {
        const float* src = (b < 256) ? W_i2h : W_h2h;
        unsigned short* dst = (b < 256) ? Wi2hb : Wh2hb;
        const int i = ((b & 255) << 8) + tid;
        float4 v = ((const float4*)src)[i];
        ushort4 o; o.x = f2bf(v.x); o.y = f2bf(v.y); o.z = f2bf(v.z); o.w = f2bf(v.w);
        ((ushort4*)dst)[i] = o;
    } else if (b < 560) {
        const int i = ((b - 512) << 8) + tid;
        float4 v = ((const float4*)W_gen)[i];
        ushort4 o; o.x = f2bf(v.x); o.y = f2bf(v.y); o.z = f2bf(v.z); o.w = f2bf(v.w);
        ((ushort4*)Wgenb)[i] = o;
    } else if (b < 1584) {
        const int isI = (b < 1072);
        const int i = ((b - (isI ? 560 : 1072)) << 8) + tid;
        const int np = i >> 6, k8 = (i & 63) << 3;
        const int h = np >> 2, g = np & 3;
        const float* p = (isI ? W_ih : W_hh) + (size_t)(g * 512 + h) * (isI ? 608 : 512) + k8;
        unsigned short* dst = isI ? Wgi : Wgh;
        float4 v0 = *(const float4*)p, v1 = *(const float4*)(p + 4);
        ushort4 o0, o1;
        o0.x = f2bf(v0.x); o0.y = f2bf(v0.y); o0.z = f2bf(v0.z); o0.w = f2bf(v0.w);
        o1.x = f2bf(v1.x); o1.y = f2bf(v1.y); o1.z = f2bf(v1.z); o1.w = f2bf(v1.w);
        *(ushort4*)(dst + (size_t)np * 512 + k8) = o0;
        *(ushort4*)(dst + (size_t)np * 512 + k8 + 4) = o1;
    } else if (b < 2352) {
        const int i = ((b - 1584) << 8) + tid;
        const int t = i >> 11, np = i & 2047;
        const int h = np >> 2, g = np & 3;
        Wtok_p[i] = W_ih[(size_t)(g * 512 + h) * 608 + 512 + t];
    } else if (b < 2360) {
        const int i = ((b - 2352) << 8) + tid;
        const int h = i >> 2, g = i & 3, n = g * 512 + h;
        bsum_p[i] = b_ih[n] + b_hh[n];
    } else if (b < 18744) {
        const int i = ((b - 2360) << 8) + tid;
        float4 v = ((const float4*)batch_H)[i];
        ushort4 o; o.x = f2bf(v.x); o.y = f2bf(v.y); o.z = f2bf(v.z); o.w = f2bf(v.w);
        ((ushort4*)bH)[i] = o;
    } else if (b < 18872) {
        ((uint4*)hbuf1)[((b - 18744) << 8) + tid] = uint4{0, 0, 0, 0};
    } else {
        ((uint4*)cst)[((b - 18872) << 8) + tid] = uint4{0, 0, 0, 0};
    }
}

// ---------------------------------------------------------------------------
// bf16 NT MFMA GEMM (proven). MODE 0: bf16 out. MODE 3: f32+bias masked.
// SWZ 1: H_proj XCD remap (grid dim3(512,8)).
// ---------------------------------------------------------------------------
template <int MODE, int SWZ>
__global__ __launch_bounds__(256) void gemm_bf16(
    const unsigned short* __restrict__ A, int lda,
    const unsigned short* __restrict__ B, int ldb,
    void* __restrict__ Cout, int ldc,
    const float* __restrict__ bias, int K, int Nreal)
{
    __shared__ unsigned short As[2][64][72];
    __shared__ unsigned short Bs[2][64][72];
    const int tid = threadIdx.x;
    int bm, bn;
    if (SWZ == 1) {
        const int l = blockIdx.x + (blockIdx.y << 9);
        const int cc = l & 7, k = l >> 3;
        bm = ((cc << 6) + (k >> 3)) << 6;
        bn = (k & 7) << 6;
    } else {
        bm = blockIdx.y << 6;
        bn = blockIdx.x << 6;
    }
    const int w = tid >> 6, lane = tid & 63;
    const int wr = w >> 1, wc = w & 1;
    const int srow = tid >> 2, schunk = (tid & 3) << 4;
    int brow = bn + srow;
    if (MODE == 3) brow = min(brow, Nreal - 1);
    const unsigned short* Ap = A + (size_t)(bm + srow) * lda + schunk;
    const unsigned short* Bp = B + (size_t)brow * ldb + schunk;
    const int fr = lane & 15, fq = lane >> 4;

    uint4 ra0, ra1, rb0, rb1;
    f32x4 acc[2][2];
#pragma unroll
    for (int i = 0; i < 2; i++)
#pragma unroll
        for (int j = 0; j < 2; j++) acc[i][j] = f32x4{0.f, 0.f, 0.f, 0.f};

    const int NTk = K >> 6;
#define LOADR(t) { ra0 = *(const uint4*)(Ap + ((t) << 6)); ra1 = *(const uint4*)(Ap + ((t) << 6) + 8); \
                   rb0 = *(const uint4*)(Bp + ((t) << 6)); rb1 = *(const uint4*)(Bp + ((t) << 6) + 8); }
#define WRITEB(cb) { *(uint4*)&As[cb][srow][schunk] = ra0; *(uint4*)&As[cb][srow][schunk + 8] = ra1; \
                     *(uint4*)&Bs[cb][srow][schunk] = rb0; *(uint4*)&Bs[cb][srow][schunk + 8] = rb1; }
    LOADR(0); WRITEB(0);
    LOADR(1);
    __syncthreads();
    for (int t = 0; t < NTk; t++) {
        const int cb = t & 1;
        if (t + 1 < NTk) WRITEB(cb ^ 1);
        if (t + 2 < NTk) LOADR(t + 2);
        bf16x8 af[2][2], bfr[2][2];
#pragma unroll
        for (int fi = 0; fi < 2; fi++)
#pragma unroll
            for (int ks = 0; ks < 2; ks++) {
                af[fi][ks]  = *(const bf16x8*)&As[cb][(wr << 5) + (fi << 4) + fr][(ks << 5) + (fq << 3)];
                bfr[fi][ks] = *(const bf16x8*)&Bs[cb][(wc << 5) + (fi << 4) + fr][(ks << 5) + (fq << 3)];
            }
#pragma unroll
        for (int fi = 0; fi < 2; fi++)
#pragma unroll
            for (int fj = 0; fj < 2; fj++)
#pragma unroll
                for (int ks = 0; ks < 2; ks++)
                    acc[fi][fj] = __builtin_amdgcn_mfma_f32_16x16x32_bf16(
                        af[fi][ks], bfr[fj][ks], acc[fi][fj], 0, 0, 0);
        __syncthreads();
    }
#undef LOADR
#undef WRITEB
#pragma unroll
    for (int fi = 0; fi < 2; fi++) {
        const int mbase = bm + (wr << 5) + (fi << 4) + (fq << 2);
#pragma unroll
        for (int fj = 0; fj < 2; fj++) {
            const int n = bn + (wc << 5) + (fj << 4) + fr;
            f32x4 v = acc[fi][fj];
            if (MODE == 0) {
                unsigned short* C = (unsigned short*)Cout;
#pragma unroll
                for (int r = 0; r < 4; r++) C[(size_t)(mbase + r) * ldc + n] = f2bf(v[r]);
            } else {
                if (n < Nreal) {
                    float* C = (float*)Cout;
                    const float bb = bias[n];
#pragma unroll
                    for (int r = 0; r < 4; r++) C[(size_t)(mbase + r) * ldc + n] = v[r] + bb;
                }
            }
        }
    }
}

// ---------------------------------------------------------------------------
// ph GEMM: 32x32 tiles, 256 blocks, wave-per-quadrant (proven R7).
// ---------------------------------------------------------------------------
__global__ __launch_bounds__(256) void gemm_ph(
    const unsigned short* __restrict__ A,   // hprev [512][512] bf16
    const unsigned short* __restrict__ B,   // Wh2hb [512][512] bf16
    float* __restrict__ C,                  // ph [512][512] f32
    const float* __restrict__ bias)
{
    __shared__ unsigned short As[2][32][72];
    __shared__ unsigned short Bs[2][32][72];
    const int tid = threadIdx.x;
    const int m0 = (blockIdx.x >> 4) << 5;
    const int n0 = (blockIdx.x & 15) << 5;
    const int w = tid >> 6, lane = tid & 63;
    const int fr = lane & 15, fq = lane >> 4;
    const int mf = w >> 1, nf = w & 1;
    const int srow = tid >> 3, schunk = (tid & 7) << 3;
    const unsigned short* Ap = A + (size_t)(m0 + srow) * 512 + schunk;
    const unsigned short* Bp = B + (size_t)(n0 + srow) * 512 + schunk;

    uint4 ra, rb;
    f32x4 acc = {0.f, 0.f, 0.f, 0.f};
    ra = *(const uint4*)Ap; rb = *(const uint4*)Bp;
    *(uint4*)&As[0][srow][schunk] = ra;
    *(uint4*)&Bs[0][srow][schunk] = rb;
    ra = *(const uint4*)(Ap + 64); rb = *(const uint4*)(Bp + 64);
    __syncthreads();
    for (int t = 0; t < 8; t++) {
        const int cb = t & 1;
        if (t + 1 < 8) { *(uint4*)&As[cb ^ 1][srow][schunk] = ra;
                         *(uint4*)&Bs[cb ^ 1][srow][schunk] = rb; }
        if (t + 2 < 8) { ra = *(const uint4*)(Ap + ((t + 2) << 6));
                         rb = *(const uint4*)(Bp + ((t + 2) << 6)); }
        const bf16x8 a0 = *(const bf16x8*)&As[cb][(mf << 4) + fr][(fq << 3)];
        const bf16x8 a1 = *(const bf16x8*)&As[cb][(mf << 4) + fr][32 + (fq << 3)];
        const bf16x8 b0 = *(const bf16x8*)&Bs[cb][(nf << 4) + fr][(fq << 3)];
        const bf16x8 b1 = *(const bf16x8*)&Bs[cb][(nf << 4) + fr][32 + (fq << 3)];
        acc = __builtin_amdgcn_mfma_f32_16x16x32_bf16(a0, b0, acc, 0, 0, 0);
        acc = __builtin_amdgcn_mfma_f32_16x16x32_bf16(a1, b1, acc, 0, 0, 0);
        __syncthreads();
    }
    const int n = n0 + (nf << 4) + fr;
    const float bb = bias[n];
#pragma unroll
    for (int r = 0; r < 4; r++)
        C[(size_t)(m0 + (mf << 4) + (fq << 2) + r) * 512 + n] = acc[r] + bb;
}

// ---------------------------------------------------------------------------
// Attention (proven R7): 512 blocks x 256 thr, ph/w hoisted into registers.
// ---------------------------------------------------------------------------
__global__ __launch_bounds__(256) void attn_kernel(
    const unsigned short* __restrict__ H_proj,   // [B*64][512] bf16
    const float* __restrict__ ph,                // [B][512] f32
    const float* __restrict__ w_score,           // [512]
    const unsigned short* __restrict__ batch_H,  // [B*64][512] bf16
    unsigned short* __restrict__ ctx)            // [B][512] bf16
{
    __shared__ float s_e[64];
    __shared__ float s_al[64];
    const int b = blockIdx.x;
    const int tid = threadIdx.x;
    const int w = tid >> 6, lane = tid & 63;
    const int h0 = lane * 8;

    const float4 p0 = *(const float4*)(ph + (size_t)b * 512 + h0);
    const float4 p1 = *(const float4*)(ph + (size_t)b * 512 + h0 + 4);
    const float4 w0 = *(const float4*)(w_score + h0);
    const float4 w1 = *(const float4*)(w_score + h0 + 4);
    const float rp[8] = {p0.x, p0.y, p0.z, p0.w, p1.x, p1.y, p1.z, p1.w};
    const float rw[8] = {w0.x, w0.y, w0.z, w0.w, w1.x, w1.y, w1.z, w1.w};

    for (int t = w; t < 64; t += 4) {
        const uint4 hv = *(const uint4*)(H_proj + ((size_t)b * 64 + t) * 512 + h0);
        unsigned int ua[4] = {hv.x, hv.y, hv.z, hv.w};
        float acc = 0.f;
#pragma unroll
        for (int j = 0; j < 4; j++) {
            const float e0 = __uint_as_float(ua[j] << 16);
            const float e1 = __uint_as_float(ua[j] & 0xffff0000u);
            acc += tanh_fast(e0 + rp[2 * j]) * rw[2 * j];
            acc += tanh_fast(e1 + rp[2 * j + 1]) * rw[2 * j + 1];
        }
#pragma unroll
        for (int off = 32; off; off >>= 1) acc += __shfl_xor(acc, off);
        if (lane == 0) s_e[t] = acc;
    }
    __syncthreads();
    if (tid < 64) {
        float m = -1e30f;
        for (int t = 0; t < 64; ++t) m = fmaxf(m, s_e[t]);
        float sum = 0.f;
        for (int t = 0; t < 64; ++t) sum += __expf(s_e[t] - m);
        s_al[tid] = __expf(s_e[tid] - m) / sum;
    }
    __syncthreads();
    const unsigned int* bHp = (const unsigned int*)(batch_H + (size_t)b * 64 * 512);
    float a0 = 0.f, a1 = 0.f;
    for (int t = 0; t < 64; ++t) {
        const unsigned int u = bHp[t * 256 + tid];
        const float al = s_al[t];
        a0 = fmaf(al, __uint_as_float(u << 16), a0);
        a1 = fmaf(al, __uint_as_float(u & 0xffff0000u), a1);
    }
    const unsigned int o = ((unsigned int)f2bf(a1) << 16) | (unsigned int)f2bf(a0);
    ((unsigned int*)(ctx + (size_t)b * 512))[tid] = o;
}

// ---------------------------------------------------------------------------
// Fused gates GEMM (gate-permuted N) + LSTM pointwise (proven R4/R7/R10).
// ---------------------------------------------------------------------------
__global__ __launch_bounds__(256) void gates_lstm(
    const unsigned short* __restrict__ ctx,
    const unsigned short* __restrict__ hprev,
    const unsigned short* __restrict__ Wgi,
    const unsigned short* __restrict__ Wgh,
    const float* __restrict__ bsum_p,
    const float* __restrict__ Wtok_p,
    const int* __restrict__ text, int sstep,
    float* __restrict__ c,
    unsigned short* __restrict__ hs,
    unsigned short* __restrict__ hnew)
{
    __shared__ __align__(16) char smem[36864];
    unsigned short (*As)[64][72] = (unsigned short(*)[64][72])smem;
    unsigned short (*Bs)[64][72] = (unsigned short(*)[64][72])(smem + 18432);
    float (*gls)[68] = (float(*)[68])smem;

    const int tid = threadIdx.x;
    const int l = blockIdx.x + (blockIdx.y << 5);
    const int cc = l & 7, kq = l >> 3;
    const int nblk = (cc << 2) + (kq >> 3);
    const int m0 = (kq & 7) << 6;
    const int bn_ = nblk << 6;
    const int w = tid >> 6, lane = tid & 63;
    const int wr = w >> 1, wc = w & 1;
    const int srow = tid >> 2, schunk = (tid & 3) << 4;
    const int fr = lane & 15, fq = lane >> 4;

    const unsigned short* Ac = ctx   + (size_t)(m0 + srow) * 512 + schunk;
    const unsigned short* Ah = hprev + (size_t)(m0 + srow) * 512 + schunk;
    const unsigned short* Bi = Wgi + (size_t)(bn_ + srow) * 512 + schunk;
    const unsigned short* Bh = Wgh + (size_t)(bn_ + srow) * 512 + schunk;

    uint4 ra0, ra1, rb0, rb1;
    f32x4 acc[2][2];
#pragma unroll
    for (int i = 0; i < 2; i++)
#pragma unroll
        for (int j = 0; j < 2; j++) acc[i][j] = f32x4{0.f, 0.f, 0.f, 0.f};

#define GLOAD(t) { const int tt = (t); \
    const unsigned short* ap = (tt < 8) ? Ac + (tt << 6) : Ah + ((tt - 8) << 6); \
    const unsigned short* bp = (tt < 8) ? Bi + (tt << 6) : Bh + ((tt - 8) << 6); \
    ra0 = *(const uint4*)ap; ra1 = *(const uint4*)(ap + 8); \
    rb0 = *(const uint4*)bp; rb1 = *(const uint4*)(bp + 8); }
#define WRITEB(cb) { *(uint4*)&As[cb][srow][schunk] = ra0; *(uint4*)&As[cb][srow][schunk + 8] = ra1; \
                     *(uint4*)&Bs[cb][srow][schunk] = rb0; *(uint4*)&Bs[cb][srow][schunk + 8] = rb1; }
    GLOAD(0); WRITEB(0);
    GLOAD(1);
    __syncthreads();
    for (int t = 0; t < 16; t++) {
        const int cb = t & 1;
        if (t + 1 < 16) WRITEB(cb ^ 1);
        if (t + 2 < 16) GLOAD(t + 2);
        bf16x8 af[2][2], bfr[2][2];
#pragma unroll
        for (int fi = 0; fi < 2; fi++)
#pragma unroll
            for (int ks = 0; ks < 2; ks++) {
                af[fi][ks]  = *(const bf16x8*)&As[cb][(wr << 5) + (fi << 4) + fr][(ks << 5) + (fq << 3)];
                bfr[fi][ks] = *(const bf16x8*)&Bs[cb][(wc << 5) + (fi << 4) + fr][(ks << 5) + (fq << 3)];
            }
#pragma unroll
        for (int fi = 0; fi < 2; fi++)
#pragma unroll
            for (int fj = 0; fj < 2; fj++)
#pragma unroll
                for (int ks = 0; ks < 2; ks++)
                    acc[fi][fj] = __builtin_amdgcn_mfma_f32_16x16x32_bf16(
                        af[fi][ks], bfr[fj][ks], acc[fi][fj], 0, 0, 0);
        __syncthreads();
    }
#undef GLOAD
#undef WRITEB
#pragma unroll
    for (int fi = 0; fi < 2; fi++)
#pragma unroll
        for (int fj = 0; fj < 2; fj++)
#pragma unroll
            for (int r = 0; r < 4; r++)
                gls[(wr << 5) + (fi << 4) + (fq << 2) + r][(wc << 5) + (fj << 4) + fr] = acc[fi][fj][r];
    __syncthreads();

    const int hbase = nblk << 4;
#pragma unroll
    for (int p = 0; p < 4; p++) {
        const int idx = (p << 8) + tid;
        const int ml = idx >> 4, hl = idx & 15;
        const int mg = m0 + ml, hg = hbase + hl;
        const int tok = text[mg * NS + sstep];
        const float4 gq = *(const float4*)&gls[ml][hl << 2];
        const float4 bq = *(const float4*)&bsum_p[bn_ + (hl << 2)];
        const float4 wq = *(const float4*)&Wtok_p[(size_t)tok * 2048 + bn_ + (hl << 2)];
        const float i_ = sigf(gq.x + bq.x + wq.x);
        const float f_ = sigf(gq.y + bq.y + wq.y);
        const float g_ = tanh_fast(gq.z + bq.z + wq.z);
        const float o_ = sigf(gq.w + bq.w + wq.w);
        const size_t ci = (size_t)mg * 512 + hg;
        const float cn = fmaf(f_, c[ci], i_ * g_);
        c[ci] = cn;
        const unsigned short hv = f2bf(o_ * tanh_fast(cn));
        hs[((size_t)mg * NS + sstep) * 512 + hg] = hv;
        hnew[ci] = hv;
    }
}

// ---------------------------------------------------------------------------
extern "C" void kernel_launch(void* const* d_in, const int* in_sizes, int n_in,
                              void* d_out, int out_size, void* d_ws, size_t ws_size,
                              hipStream_t stream) {
    const float* batch_H = (const float*)d_in[0];
    const int*   text    = (const int*)d_in[1];
    const float* W_i2h   = (const float*)d_in[2];
    const float* W_h2h   = (const float*)d_in[3];
    const float* b_h2h   = (const float*)d_in[4];
    const float* w_score = (const float*)d_in[5];
    const float* W_ih    = (const float*)d_in[6];
    const float* b_ih    = (const float*)d_in[7];
    const float* W_hh    = (const float*)d_in[8];
    const float* b_hh    = (const float*)d_in[9];
    const float* W_gen   = (const float*)d_in[10];
    const float* b_gen   = (const float*)d_in[11];
    float* out = (float*)d_out;

    char* wsp = (char*)d_ws;
    auto alloc = [&](size_t bytes) { char* p = wsp; wsp += (bytes + 255) & ~(size_t)255; return p; };
    unsigned short* bH    = (unsigned short*)alloc(32768ull * 512 * 2);
    unsigned short* Hproj = (unsigned short*)alloc(32768ull * 512 * 2);
    unsigned short* hs    = (unsigned short*)alloc(512ull * NS * 512 * 2);
    unsigned short* hbuf0 = (unsigned short*)alloc(512ull * 512 * 2);
    unsigned short* hbuf1 = (unsigned short*)alloc(512ull * 512 * 2);
    unsigned short* ctx   = (unsigned short*)alloc(512ull * 512 * 2);
    unsigned short* Wi2hb = (unsigned short*)alloc(512ull * 512 * 2);
    unsigned short* Wh2hb = (unsigned short*)alloc(512ull * 512 * 2);
    unsigned short* Wgi   = (unsigned short*)alloc(2048ull * 512 * 2);
    unsigned short* Wgh   = (unsigned short*)alloc(2048ull * 512 * 2);
    unsigned short* Wgenb = (unsigned short*)alloc(96ull * 512 * 2);
    float* ph     = (float*)alloc(512ull * 512 * 4);
    float* cst    = (float*)alloc(512ull * 512 * 4);
    float* bsum_p = (float*)alloc(2048ull * 4);
    float* Wtok_p = (float*)alloc(96ull * 2048 * 4);
    unsigned short* hb[2] = {hbuf0, hbuf1};

    setup_all<<<19128, 256, 0, stream>>>(W_i2h, W_h2h, W_gen, W_ih, W_hh, b_ih, b_hh,
                                         batch_H, Wi2hb, Wh2hb, Wgenb, Wgi, Wgh,
                                         Wtok_p, bsum_p, bH, hbuf1, cst);

    // H_proj = batch_H @ W_i2h^T -> bf16 [32768,512], XCD-swizzled
    gemm_bf16<0, 1><<<dim3(512, 8), 256, 0, stream>>>(bH, 512, Wi2hb, 512, Hproj, 512, nullptr, 512, 0);

    for (int s = 0; s < NS; ++s) {
        const unsigned short* hprev = hb[(s + 1) & 1];
        gemm_ph<<<256, 256, 0, stream>>>(hprev, Wh2hb, ph, b_h2h);
        attn_kernel<<<512, 256, 0, stream>>>(Hproj, ph, w_score, bH, ctx);
        gates_lstm<<<dim3(32, 8), 256, 0, stream>>>(
            ctx, hprev, Wgi, Wgh, bsum_p, Wtok_p, text, s, cst, hs, hb[s & 1]);
    }

    // out = hs @ W_gen^T + b_gen (f32, N=96 masked in 128-wide tiles)
    gemm_bf16<3, 0><<<dim3(2, 208), 256, 0, stream>>>(hs, 512, Wgenb, 512, out, 96, b_gen, 512, 96);
}